// Round 10
// baseline (468.324 us; speedup 1.0000x reference)
//
#include <hip/hip_runtime.h>

// DigitCaps dynamic routing, MI355X — round 10.
// vs r9 (290us): (a) routed passes 512-thr/8-wave blocks, 2 blocks/CU (barrier
// gap-filling); (b) plain s_part stores + squash_reduce instead of 8.4M
// atomicAdd + memsets; (c) conv_w deleted — pass A streams fp32 W, converts
// in-register (v_cvt_pk_bf16_f32), emits Wt for passes B/C.
//
// u_hat[b,j,i,p] = sum_q x[b,i,q] W[j,i,p,q];  b=64, i=2048, j=32, p=32, q=16
// Pass A: s1 = (1/32) sum_i u_hat ; v1 = squash(s1)      (emits Wt bf16)
// Pass B: per i: d=sum_p v1*u_hat ; c=softmax_j d ; s2 += c*u_hat ; v2=squash
// Pass C: v = v1+v2 (logits linear in v) ; out = squash(s3)
//
// MFMA 16x16x32 bf16: A k0-15 = hi(x), k16-31 = lo residual; B k-halves
// replicate W => A-side fp32-exact, only W rounded once (absmax ~4e-3).
// Block: 8 waves; wave = 4 j x 16 b (block's b-group); all 32 j in-block.
// Grid 512 = 4 bg x 128 it; XCD swizzle: 4 bg-blocks of an it share L2.

namespace {

using bfrag = __attribute__((ext_vector_type(8))) short;   // 8 bf16 = 4 VGPR
using ffrag = __attribute__((ext_vector_type(4))) float;   // 4 fp32

constexpr int I_DIM = 2048;
constexpr int B_DIM = 64;
constexpr int N_DIM = 1024;
constexpr int TI    = 16;
constexpr int NIT   = I_DIM / TI;   // 128

__device__ __forceinline__ unsigned short f2bf(float f) {
    unsigned int u = __float_as_uint(f);
    return (unsigned short)((u + 0x7fffu + ((u >> 16) & 1u)) >> 16);
}
__device__ __forceinline__ unsigned int cvtpk(float lo, float hi) {
    unsigned int r;
    asm("v_cvt_pk_bf16_f32 %0, %1, %2" : "=v"(r) : "v"(lo), "v"(hi));
    return r;
}
__device__ __forceinline__ float bflo(unsigned int u) { return __uint_as_float(u << 16); }
__device__ __forceinline__ float bfhi(unsigned int u) { return __uint_as_float(u & 0xffff0000u); }

template<int CTRL>
__device__ __forceinline__ float dppf(float x) {
    return __int_as_float(
        __builtin_amdgcn_update_dpp(0, __float_as_int(x), CTRL, 0xF, 0xF, true));
}
__device__ __forceinline__ float sum16(float x) {
    x += dppf<0x121>(x); x += dppf<0x122>(x);
    x += dppf<0x124>(x); x += dppf<0x128>(x);
    return x;
}
__device__ __forceinline__ float max16(float x) {
    x = fmaxf(x, dppf<0x121>(x)); x = fmaxf(x, dppf<0x122>(x));
    x = fmaxf(x, dppf<0x124>(x)); x = fmaxf(x, dppf<0x128>(x));
    return x;
}
__device__ __forceinline__ void barrier_lgkm() {
    asm volatile("s_waitcnt lgkmcnt(0)" ::: "memory");
    __builtin_amdgcn_s_barrier();
    __builtin_amdgcn_sched_barrier(0);
}

// xT2[i][g][b][8] <- x[b][i][q] fp32  (g0/1 = hi q0-7/q8-15, g2/3 = lo residual)
__global__ __launch_bounds__(256)
void conv_x(const float* __restrict__ x, unsigned short* __restrict__ xT2) {
    const int t = blockIdx.x * 256 + threadIdx.x;          // (i,b)
    const int i = t >> 6, b = t & 63;
    const float* src = x + (((size_t)b * I_DIM + i) << 4);
    unsigned int o[16];
    #pragma unroll
    for (int k = 0; k < 8; ++k) {
        const float f0 = src[2 * k], f1 = src[2 * k + 1];
        const unsigned short h0 = f2bf(f0), h1 = f2bf(f1);
        const float l0 = f0 - __uint_as_float(((unsigned int)h0) << 16);
        const float l1 = f1 - __uint_as_float(((unsigned int)h1) << 16);
        o[k]     = (unsigned int)h0       | ((unsigned int)h1 << 16);
        o[8 + k] = (unsigned int)f2bf(l0) | ((unsigned int)f2bf(l1) << 16);
    }
    #pragma unroll
    for (int g = 0; g < 4; ++g) {
        uint4* dst = reinterpret_cast<uint4*>(xT2 + (((size_t)i * 4 + g) * 64 + b) * 8);
        *dst = make_uint4(o[4 * g], o[4 * g + 1], o[4 * g + 2], o[4 * g + 3]);
    }
}

// ---------------- fused pass ----------------
// ROUTED=0: stream fp32 W, cvt_pk->bf16 in-reg, write Wt (bg0, g<2), MFMA-acc.
// ROUTED=1: read Wt; per i: round1 (u, logits via DPP) -> B1 -> softmax
//           (512 thr = 16 b x 32 j) -> B2 -> round2 (recompute u, apply c).
template<int ROUTED>
__global__ __launch_bounds__(512, 4)
void caps_pass3(const float* __restrict__ Wf,            // [J][I][P][Q] (A)
                unsigned short* __restrict__ Wt_out,     // [I][2][1024][8] (A)
                const unsigned short* __restrict__ Wt,   // (B/C)
                const unsigned short* __restrict__ xT2,  // [I][4][64][8]
                const float* __restrict__ v_in,          // [64][32][32] (B/C)
                float* __restrict__ sp_out)              // [NIT][64][1024]
{
    __shared__ float d_buf[16 * 36];
    __shared__ float c_buf[16 * 36];

    const int tid = threadIdx.x;
    const int w   = tid >> 6;          // wave 0..7
    const int l   = tid & 63;
    const int g   = l >> 4;            // 16-lane group (k-chunk)
    const int li  = l & 15;
    const int j0  = w << 2;            // 4 j per wave
    const int qb  = (g & 1) << 3;

    // XCD swizzle: V consecutive -> same i-tile's 4 bg-blocks on one XCD.
    const int bid = (int)blockIdx.x;
    const int V   = ((bid & 7) << 6) | (bid >> 3);
    const int it  = V >> 2;
    const int bg  = V & 3;
    const int b0  = bg << 4;
    const int i0  = it << 4;

    // v packed bf16x2 (p=li | p=li+16): vr[r][jj]
    unsigned int vr[4][4];
    if (ROUTED) {
        #pragma unroll
        for (int r = 0; r < 4; ++r)
            #pragma unroll
            for (int jj = 0; jj < 4; ++jj) {
                const float* vp = v_in + (((b0 + (g << 2) + r) << 5) + j0 + jj) * 32;
                vr[r][jj] = cvtpk(vp[li], vp[li + 16]);
            }
    }

    ffrag s[8];
    #pragma unroll
    for (int t = 0; t < 8; ++t) s[t] = ffrag{0.f, 0.f, 0.f, 0.f};

    for (int ii = 0; ii < TI; ++ii) {
        const int i = i0 + ii;
        const bfrag A0 = *reinterpret_cast<const bfrag*>(
            xT2 + ((size_t)i << 11) + (g << 9) + ((b0 + li) << 3));

        if constexpr (!ROUTED) {
            // stream fp32 W -> cvt -> (store Wt once) -> MFMA accumulate
            #pragma unroll
            for (int t = 0; t < 8; ++t) {
                const int jj = t >> 1, ph = t & 1;
                const float* wp = Wf + ((size_t)(j0 + jj) * I_DIM + i) * 512
                                     + ((ph << 4) + li) * 16 + qb;
                const float4 wa = *reinterpret_cast<const float4*>(wp);
                const float4 wb = *reinterpret_cast<const float4*>(wp + 4);
                union { uint4 u; bfrag b; } cv;
                cv.u = make_uint4(cvtpk(wa.x, wa.y), cvtpk(wa.z, wa.w),
                                  cvtpk(wb.x, wb.y), cvtpk(wb.z, wb.w));
                if (bg == 0 && g < 2)
                    *reinterpret_cast<bfrag*>(
                        Wt_out + ((size_t)i << 14) + ((g & 1) << 13)
                               + ((((j0 + jj) << 5) + (ph << 4) + li) << 3)) = cv.b;
                s[t] = __builtin_amdgcn_mfma_f32_16x16x32_bf16(A0, cv.b, s[t], 0, 0, 0);
            }
        } else {
            const unsigned short* xb = Wt + ((size_t)i << 14) + ((g & 1) << 13);
            bfrag B[8];
            #pragma unroll
            for (int t = 0; t < 8; ++t)
                B[t] = *reinterpret_cast<const bfrag*>(
                    xb + ((((j0 + (t >> 1)) << 5) + ((t & 1) << 4) + li) << 3));

            const ffrag z{0.f, 0.f, 0.f, 0.f};
            // ---- round 1: u + logits ----
            ffrag u[8];
            #pragma unroll
            for (int t = 0; t < 8; ++t)
                u[t] = __builtin_amdgcn_mfma_f32_16x16x32_bf16(A0, B[t], z, 0, 0, 0);

            float dd[4][4];
            #pragma unroll
            for (int r = 0; r < 4; ++r)
                #pragma unroll
                for (int jj = 0; jj < 4; ++jj) {
                    const unsigned int v2 = vr[r][jj];
                    dd[r][jj] = sum16(u[2 * jj][r] * bflo(v2)
                                    + u[2 * jj + 1][r] * bfhi(v2));
                }
            #pragma unroll
            for (int r = 0; r < 4; ++r) {
                float sel = dd[r][0];
                sel = (li == 1) ? dd[r][1] : sel;
                sel = (li == 2) ? dd[r][2] : sel;
                sel = (li == 3) ? dd[r][3] : sel;
                if (li < 4) d_buf[((g << 2) + r) * 36 + j0 + li] = sel;
            }
            barrier_lgkm();   // B1: d_buf ready

            // ---- softmax over j: 16 b-rows x 32 j = all 512 threads ----
            {
                const int row = tid >> 5, jx = tid & 31;
                const float dv = d_buf[row * 36 + jx];
                float m = max16(dv);
                m = fmaxf(m, __shfl_xor(m, 16));
                const float e = __expf(dv - m);
                float sm = sum16(e);
                sm += __shfl_xor(sm, 16);
                c_buf[row * 36 + jx] = e / sm;
            }
            barrier_lgkm();   // B2: c_buf ready

            // ---- round 2: recompute u, apply c ----
            ffrag c4[4];
            #pragma unroll
            for (int r = 0; r < 4; ++r)
                c4[r] = *reinterpret_cast<const ffrag*>(
                    &c_buf[((g << 2) + r) * 36 + j0]);
            #pragma unroll
            for (int t = 0; t < 8; ++t) {
                const ffrag u2 = __builtin_amdgcn_mfma_f32_16x16x32_bf16(A0, B[t], z, 0, 0, 0);
                #pragma unroll
                for (int r = 0; r < 4; ++r)
                    s[t][r] += c4[r][t >> 1] * u2[r];
            }
        }
    }

    // plain coalesced partial stores (no atomics, no memset needed)
    const float sc = ROUTED ? 1.f : (1.f / 32.f);
    #pragma unroll
    for (int t = 0; t < 8; ++t) {
        const int n0 = ((j0 + (t >> 1)) << 5) + ((t & 1) << 4);
        #pragma unroll
        for (int r = 0; r < 4; ++r)
            sp_out[(((size_t)(it << 6) + b0 + (g << 2) + r) << 10) + n0 + li]
                = s[t][r] * sc;
    }
}

// dst[row] = (base ? base[row] : 0) + squash(sum_it s_part[it][row]), row=(b,j)
__global__ __launch_bounds__(256)
void squash_reduce(const float* __restrict__ s_part,
                   const float* __restrict__ base,
                   float* __restrict__ dst) {
    const int tid = threadIdx.x;
    const int rr  = blockIdx.x * 8 + (tid >> 5);    // row 0..2047
    const int p   = tid & 31;
    const int b   = rr >> 5, jx = rr & 31;
    const float* sp = s_part + (size_t)b * N_DIM + (jx << 5) + p;
    float a0 = 0.f, a1 = 0.f, a2 = 0.f, a3 = 0.f;
    for (int it2 = 0; it2 < NIT; it2 += 4) {
        a0 += sp[(size_t)(it2 + 0) << 16];
        a1 += sp[(size_t)(it2 + 1) << 16];
        a2 += sp[(size_t)(it2 + 2) << 16];
        a3 += sp[(size_t)(it2 + 3) << 16];
    }
    const float sv = (a0 + a1) + (a2 + a3);
    float n2 = sv * sv;
    n2 = sum16(n2);
    n2 += __shfl_xor(n2, 16);
    const float scl = n2 / ((1.f + n2) * sqrtf(n2 + 1e-7f));
    dst[rr * 32 + p] = (base ? base[rr * 32 + p] : 0.f) + scl * sv;
}

} // namespace

extern "C" void kernel_launch(void* const* d_in, const int* in_sizes, int n_in,
                              void* d_out, int out_size, void* d_ws, size_t ws_size,
                              hipStream_t stream) {
    const float* x = (const float*)d_in[0];   // [64, 2048, 16]
    const float* W = (const float*)d_in[1];   // [32, 2048, 32, 16]
    float* out = (float*)d_out;               // [64, 32, 32]

    const size_t needW = (size_t)I_DIM * 2 * 1024 * 8 * 2;    // 64 MB bf16 Wt
    const size_t needX = (size_t)I_DIM * 4 * 64 * 8 * 2;      //  8 MB bf16 xT2
    const size_t needP = (size_t)NIT * B_DIM * N_DIM * 4;     // 32 MB partials
    const size_t needV = (size_t)B_DIM * N_DIM * 4;           // 256 KB

    char* pp = (char*)d_ws;
    unsigned short* Wt  = (unsigned short*)pp; pp += needW;
    unsigned short* xT2 = (unsigned short*)pp; pp += needX;
    float* s_part = (float*)pp; pp += needP;
    float* v1     = (float*)pp; pp += needV;
    float* vs     = (float*)pp;
    (void)ws_size;

    conv_x<<<(I_DIM * B_DIM) / 256, 256, 0, stream>>>(x, xT2);

    const dim3 rg(512), rb(512);
    const dim3 qg(256), qb(256);

    // pass A: uniform c = 1/32 (streams fp32 W; emits Wt)
    caps_pass3<0><<<rg, rb, 0, stream>>>(W, Wt, nullptr, xT2, nullptr, s_part);
    squash_reduce<<<qg, qb, 0, stream>>>(s_part, nullptr, v1);

    // pass B: v = v1
    caps_pass3<1><<<rg, rb, 0, stream>>>(nullptr, nullptr, Wt, xT2, v1, s_part);
    squash_reduce<<<qg, qb, 0, stream>>>(s_part, v1, vs);     // vs = v1 + v2

    // pass C: v = v1+v2 (logits linear in v)
    caps_pass3<1><<<rg, rb, 0, stream>>>(nullptr, nullptr, Wt, xT2, vs, s_part);
    squash_reduce<<<qg, qb, 0, stream>>>(s_part, nullptr, out);
}

// Round 11
// 277.303 us; speedup vs baseline: 1.6889x; 1.6889x over previous
//
#include <hip/hip_runtime.h>

// DigitCaps dynamic routing, MI355X — round 11: r8 structure + 2-deep
// register prefetch in the sweeps (single change; r10 fully reverted).
//
// u_hat[b,j,i,p] = sum_q x[b,i,q] W[j,i,p,q];  b=64, i=2048, j=32, p=32, q=16
//   A-sweep:  s1 = (1/32) sum_i u_hat            -> s_part ; v1 = squash
//   D-sweep:  d[i][j][b] = sum_p v[b,j,p]*u_hat  (v = v1, then v1+v2)
//   softmax:  c[i][j][b] = softmax_j d           (per-thread row)
//   S-sweep:  s = sum_i c*u_hat                  -> s_part ; squash -> v2/out
// Pass-C logits = sum_p (v1+v2)*u_hat (linearity) -> only 2 D-sweeps.
//
// Sweep: 256 thr = 4 waves (wave = 1 j, all 64 b), grid 1024 = 8 jg x 128 it,
// barrier-free, no LDS. NEW vs r8: frags for i+2 loaded while computing i
// (static named slots, no runtime-indexed arrays), incremental pointers,
// v packed bf16x2 (16 regs). Tail prefetch reads 2 i-strides past the tile:
// always inside ws (harmless garbage, results unused).
//
// MFMA 16x16x32 bf16: A k0-15 = hi(x), k16-31 = lo residual; B k-halves
// replicate W => A-side fp32-exact, only W rounded once (absmax ~4e-3).
// Layouts: Wt[i][h][n][8] bf16 (h=q-half, n=j*32+p), xT2[i][g][b][8] bf16.

namespace {

using bfrag = __attribute__((ext_vector_type(8))) short;   // 8 bf16 = 4 VGPR
using ffrag = __attribute__((ext_vector_type(4))) float;   // 4 fp32

constexpr int I_DIM = 2048;
constexpr int B_DIM = 64;
constexpr int N_DIM = 1024;
constexpr int TI    = 16;          // i's per block
constexpr int NIT   = I_DIM / TI;  // 128 i-tiles

__device__ __forceinline__ unsigned short f2bf(float f) {
    unsigned int u = __float_as_uint(f);
    return (unsigned short)((u + 0x7fffu + ((u >> 16) & 1u)) >> 16);
}
__device__ __forceinline__ unsigned int cvtpk(float lo, float hi) {
    unsigned int r;
    asm("v_cvt_pk_bf16_f32 %0, %1, %2" : "=v"(r) : "v"(lo), "v"(hi));
    return r;
}
__device__ __forceinline__ float bflo(unsigned int u) { return __uint_as_float(u << 16); }
__device__ __forceinline__ float bfhi(unsigned int u) { return __uint_as_float(u & 0xffff0000u); }

template<int CTRL>
__device__ __forceinline__ float dppf(float x) {
    return __int_as_float(
        __builtin_amdgcn_update_dpp(0, __float_as_int(x), CTRL, 0xF, 0xF, true));
}
__device__ __forceinline__ float sum16(float x) {   // reduce within 16-lane row
    x += dppf<0x121>(x); x += dppf<0x122>(x);
    x += dppf<0x124>(x); x += dppf<0x128>(x);
    return x;
}

// ---------------- conversion kernels (r8-proven) ----------------

// Wt[i][h][n][8] <- W[j][i][p][q] fp32  (n = j*32+p, h = q-half)
__global__ __launch_bounds__(256)
void conv_w(const float* __restrict__ W, unsigned short* __restrict__ Wt) {
    const int t = blockIdx.x * 256 + threadIdx.x;          // (i,n)
    const int i = t >> 10, n = t & 1023;
    const float* src = W + ((((n >> 5) * I_DIM + i) * 32 + (n & 31)) << 4);
    unsigned int o[8];
    #pragma unroll
    for (int k = 0; k < 8; ++k)
        o[k] = (unsigned int)f2bf(src[2 * k]) | ((unsigned int)f2bf(src[2 * k + 1]) << 16);
    uint4* d0 = reinterpret_cast<uint4*>(Wt + (((size_t)i * 2 + 0) * 1024 + n) * 8);
    uint4* d1 = reinterpret_cast<uint4*>(Wt + (((size_t)i * 2 + 1) * 1024 + n) * 8);
    *d0 = make_uint4(o[0], o[1], o[2], o[3]);
    *d1 = make_uint4(o[4], o[5], o[6], o[7]);
}

// xT2[i][g][b][8] <- x[b][i][q] fp32  (g0/1 = hi q0-7/q8-15, g2/3 = lo residual)
__global__ __launch_bounds__(256)
void conv_x(const float* __restrict__ x, unsigned short* __restrict__ xT2) {
    const int t = blockIdx.x * 256 + threadIdx.x;          // (i,b)
    const int i = t >> 6, b = t & 63;
    const float* src = x + (((size_t)b * I_DIM + i) << 4);
    unsigned int o[16];
    #pragma unroll
    for (int k = 0; k < 8; ++k) {
        const float f0 = src[2 * k], f1 = src[2 * k + 1];
        const unsigned short h0 = f2bf(f0), h1 = f2bf(f1);
        const float l0 = f0 - __uint_as_float(((unsigned int)h0) << 16);
        const float l1 = f1 - __uint_as_float(((unsigned int)h1) << 16);
        o[k]     = (unsigned int)h0       | ((unsigned int)h1 << 16);
        o[8 + k] = (unsigned int)f2bf(l0) | ((unsigned int)f2bf(l1) << 16);
    }
    #pragma unroll
    for (int g = 0; g < 4; ++g) {
        uint4* dst = reinterpret_cast<uint4*>(xT2 + (((size_t)i * 4 + g) * 64 + b) * 8);
        *dst = make_uint4(o[4 * g], o[4 * g + 1], o[4 * g + 2], o[4 * g + 3]);
    }
}

// ---------------- MFMA sweeps (barrier-free, all-b, 2-deep prefetch) -------
// MODE 0 (A): s[bg][t] accumulates u_hat via MFMA C-operand.
// MODE 1 (D): u -> dv[r] = sum_p v*u (DPP), lanes li<4 store d[i][j][b].
// MODE 2 (S): u -> s += c4[bg][r]*u (c broadcast float4 per bg).
template<int MODE>
__global__ __launch_bounds__(256, 4)
void caps_sweep(const unsigned short* __restrict__ Wt,   // [I][2][1024][8]
                const unsigned short* __restrict__ xT2,  // [I][4][64][8]
                const float* __restrict__ v_in,          // [64][32][32] (D)
                const float* __restrict__ c_in,          // [I][32][64]  (S)
                float* __restrict__ d_out,               // [I][32][64]  (D)
                float* __restrict__ sp_out)              // [NIT][64][1024] (A,S)
{
    const int tid = threadIdx.x;
    const int w  = tid >> 6;           // wave 0..3 (j within group)
    const int l  = tid & 63;
    const int g  = l >> 4;             // 16-lane group 0..3
    const int li = l & 15;

    // XCD-chunk bijective swizzle (1024 % 8 == 0): consecutive V = same
    // i-tile, 8 jg co-timed on one XCD (x-slice dedups in its L2).
    const int bid = (int)blockIdx.x;
    const int V   = ((bid & 7) << 7) | (bid >> 3);
    const int it  = ((V >> 7) << 4) | ((V & 127) >> 3);   // 0..127
    const int jg  = V & 7;
    const int j   = (jg << 2) + w;                        // 0..31
    const int i0  = it << 4;

    // per-lane element offsets (shorts)
    const int aoff = ((g << 6) + li) << 3;                        // xT2 lane off
    const int boff = ((((g & 1) << 10) + (j << 5) + li)) << 3;    // Wt lane off

    // v packed bf16x2 (p=li | p=li+16): vr[bg][r]  (D only, 16 regs)
    unsigned int vr[4][4];
    if (MODE == 1) {
        #pragma unroll
        for (int bg = 0; bg < 4; ++bg)
            #pragma unroll
            for (int r = 0; r < 4; ++r) {
                const float* vp = v_in + ((((bg << 4) + (g << 2) + r) << 5) + j) * 32;
                vr[bg][r] = cvtpk(vp[li], vp[li + 16]);
            }
    }

    ffrag s[4][2];
    #pragma unroll
    for (int bg = 0; bg < 4; ++bg) {
        s[bg][0] = ffrag{0.f, 0.f, 0.f, 0.f};
        s[bg][1] = ffrag{0.f, 0.f, 0.f, 0.f};
    }

    // rolling base pointers: advance by 2 i per cc-iteration
    const unsigned short* pa = xT2 + (size_t)i0 * 2048 + aoff;
    const unsigned short* pb = Wt + (size_t)i0 * 16384 + boff;

    bfrag A0[4], B0[2], A1[4], B1[2];
    #pragma unroll
    for (int bg = 0; bg < 4; ++bg) {
        A0[bg] = *reinterpret_cast<const bfrag*>(pa + (bg << 7));
        A1[bg] = *reinterpret_cast<const bfrag*>(pa + 2048 + (bg << 7));
    }
    B0[0] = *reinterpret_cast<const bfrag*>(pb);
    B0[1] = *reinterpret_cast<const bfrag*>(pb + 128);
    B1[0] = *reinterpret_cast<const bfrag*>(pb + 16384);
    B1[1] = *reinterpret_cast<const bfrag*>(pb + 16384 + 128);

    // body: consume (CA,CB) for index i; refill SAME slot from pa/pb + off
    // (i+2; last iters read 1-2 i-strides past the tile — allocated, unused).
    auto body = [&](int i, bfrag (&CA)[4], bfrag (&CB)[2],
                    int offA, int offB) {
        if (MODE == 0) {
            #pragma unroll
            for (int bg = 0; bg < 4; ++bg) {
                s[bg][0] = __builtin_amdgcn_mfma_f32_16x16x32_bf16(CA[bg], CB[0], s[bg][0], 0, 0, 0);
                s[bg][1] = __builtin_amdgcn_mfma_f32_16x16x32_bf16(CA[bg], CB[1], s[bg][1], 0, 0, 0);
            }
            // refill (after MFMA issue, WAR clears at issue)
            #pragma unroll
            for (int bg = 0; bg < 4; ++bg)
                CA[bg] = *reinterpret_cast<const bfrag*>(pa + offA + (bg << 7));
            CB[0] = *reinterpret_cast<const bfrag*>(pb + offB);
            CB[1] = *reinterpret_cast<const bfrag*>(pb + offB + 128);
        } else if (MODE == 1) {
            const ffrag z{0.f, 0.f, 0.f, 0.f};
            ffrag u0[4], u1[4];
            #pragma unroll
            for (int bg = 0; bg < 4; ++bg) {
                u0[bg] = __builtin_amdgcn_mfma_f32_16x16x32_bf16(CA[bg], CB[0], z, 0, 0, 0);
                u1[bg] = __builtin_amdgcn_mfma_f32_16x16x32_bf16(CA[bg], CB[1], z, 0, 0, 0);
            }
            #pragma unroll
            for (int bg = 0; bg < 4; ++bg)
                CA[bg] = *reinterpret_cast<const bfrag*>(pa + offA + (bg << 7));
            CB[0] = *reinterpret_cast<const bfrag*>(pb + offB);
            CB[1] = *reinterpret_cast<const bfrag*>(pb + offB + 128);

            #pragma unroll
            for (int bg = 0; bg < 4; ++bg) {
                float d0 = sum16(u0[bg][0] * bflo(vr[bg][0]) + u1[bg][0] * bfhi(vr[bg][0]));
                float d1 = sum16(u0[bg][1] * bflo(vr[bg][1]) + u1[bg][1] * bfhi(vr[bg][1]));
                float d2 = sum16(u0[bg][2] * bflo(vr[bg][2]) + u1[bg][2] * bfhi(vr[bg][2]));
                float d3 = sum16(u0[bg][3] * bflo(vr[bg][3]) + u1[bg][3] * bfhi(vr[bg][3]));
                float sel = d0;
                sel = (li == 1) ? d1 : sel;
                sel = (li == 2) ? d2 : sel;
                sel = (li == 3) ? d3 : sel;
                if (li < 4)
                    d_out[((size_t)i << 11) + (j << 6) + (bg << 4) + (g << 2) + li] = sel;
            }
        } else {
            ffrag c4[4];
            const float* cb = c_in + ((size_t)i << 11) + (j << 6) + (g << 2);
            #pragma unroll
            for (int bg = 0; bg < 4; ++bg)
                c4[bg] = *reinterpret_cast<const ffrag*>(cb + (bg << 4));
            const ffrag z{0.f, 0.f, 0.f, 0.f};
            #pragma unroll
            for (int bg = 0; bg < 4; ++bg) {
                const ffrag u0 = __builtin_amdgcn_mfma_f32_16x16x32_bf16(CA[bg], CB[0], z, 0, 0, 0);
                const ffrag u1 = __builtin_amdgcn_mfma_f32_16x16x32_bf16(CA[bg], CB[1], z, 0, 0, 0);
                #pragma unroll
                for (int r = 0; r < 4; ++r) {
                    s[bg][0][r] += c4[bg][r] * u0[r];
                    s[bg][1][r] += c4[bg][r] * u1[r];
                }
            }
            #pragma unroll
            for (int bg = 0; bg < 4; ++bg)
                CA[bg] = *reinterpret_cast<const bfrag*>(pa + offA + (bg << 7));
            CB[0] = *reinterpret_cast<const bfrag*>(pb + offB);
            CB[1] = *reinterpret_cast<const bfrag*>(pb + offB + 128);
        }
    };

    for (int cc = 0; cc < TI / 2; ++cc) {
        const int i = i0 + 2 * cc;
        body(i,     A0, B0, 2 * 2048, 2 * 16384);   // refill slot0 <- i+2
        body(i + 1, A1, B1, 3 * 2048, 3 * 16384);   // refill slot1 <- i+3
        pa += 2 * 2048;
        pb += 2 * 16384;
    }

    if (MODE != 1) {
        const float sc = (MODE == 0) ? (1.f / 32.f) : 1.f;
        #pragma unroll
        for (int bg = 0; bg < 4; ++bg)
            #pragma unroll
            for (int t = 0; t < 2; ++t)
                #pragma unroll
                for (int r = 0; r < 4; ++r)
                    sp_out[((size_t)((it << 6) + (bg << 4) + (g << 2) + r) << 10)
                           + (j << 5) + (t << 4) + li] = s[bg][t][r] * sc;
    }
}

// c[i][j][b] = softmax_j d[i][j][b] — one thread per (i,b), row in registers
__global__ __launch_bounds__(256)
void softmax_dc(const float* __restrict__ d, float* __restrict__ c) {
    const int t = blockIdx.x * 256 + threadIdx.x;   // (i,b)
    const int i = t >> 6, b = t & 63;
    const float* dp = d + ((size_t)i << 11) + b;
    float v[32];
    float m = -1e30f;
    #pragma unroll
    for (int jx = 0; jx < 32; ++jx) { v[jx] = dp[jx << 6]; m = fmaxf(m, v[jx]); }
    float sm = 0.f;
    #pragma unroll
    for (int jx = 0; jx < 32; ++jx) { v[jx] = __expf(v[jx] - m); sm += v[jx]; }
    const float inv = 1.f / sm;
    float* cp = c + ((size_t)i << 11) + b;
    #pragma unroll
    for (int jx = 0; jx < 32; ++jx) cp[jx << 6] = v[jx] * inv;
}

// dst[row] = (base ? base[row] : 0) + squash(sum_it s_part[it][row]), row=(b,j)
__global__ __launch_bounds__(256)
void squash_reduce(const float* __restrict__ s_part,
                   const float* __restrict__ base,
                   float* __restrict__ dst) {
    const int tid = threadIdx.x;
    const int rr  = blockIdx.x * 8 + (tid >> 5);    // row 0..2047
    const int p   = tid & 31;
    const int b   = rr >> 5, jx = rr & 31;
    const float* sp = s_part + (size_t)b * N_DIM + (jx << 5) + p;
    float a0 = 0.f, a1 = 0.f, a2 = 0.f, a3 = 0.f;
    for (int it2 = 0; it2 < NIT; it2 += 4) {
        a0 += sp[(size_t)(it2 + 0) << 16];
        a1 += sp[(size_t)(it2 + 1) << 16];
        a2 += sp[(size_t)(it2 + 2) << 16];
        a3 += sp[(size_t)(it2 + 3) << 16];
    }
    const float sv = (a0 + a1) + (a2 + a3);
    float n2 = sv * sv;
    n2 = sum16(n2);
    n2 += __shfl_xor(n2, 16);
    const float scl = n2 / ((1.f + n2) * sqrtf(n2 + 1e-7f));
    dst[rr * 32 + p] = (base ? base[rr * 32 + p] : 0.f) + scl * sv;
}

} // namespace

extern "C" void kernel_launch(void* const* d_in, const int* in_sizes, int n_in,
                              void* d_out, int out_size, void* d_ws, size_t ws_size,
                              hipStream_t stream) {
    const float* x = (const float*)d_in[0];   // [64, 2048, 16]
    const float* W = (const float*)d_in[1];   // [32, 2048, 32, 16]
    float* out = (float*)d_out;               // [64, 32, 32]

    const size_t needW = (size_t)I_DIM * 2 * 1024 * 8 * 2;    // 64 MB bf16 Wt
    const size_t needX = (size_t)I_DIM * 4 * 64 * 8 * 2;      //  8 MB bf16 xT2
    const size_t needD = (size_t)I_DIM * 32 * 64 * 4;         // 16 MB d / c
    const size_t needP = (size_t)NIT * B_DIM * N_DIM * 4;     // 32 MB partials
    const size_t needV = (size_t)B_DIM * N_DIM * 4;           // 256 KB

    char* pp = (char*)d_ws;
    unsigned short* Wt  = (unsigned short*)pp; pp += needW;
    unsigned short* xT2 = (unsigned short*)pp; pp += needX;   // tail prefetch
    float* dbuf   = (float*)pp; pp += needD;                  //  spills into
    float* cbuf   = (float*)pp; pp += needD;                  //  next region:
    float* s_part = (float*)pp; pp += needP;                  //  allocated, ok
    float* v1     = (float*)pp; pp += needV;
    float* vs     = (float*)pp;
    (void)ws_size;

    conv_x<<<(I_DIM * B_DIM) / 256, 256, 0, stream>>>(x, xT2);
    conv_w<<<(I_DIM * N_DIM) / 256, 256, 0, stream>>>(W, Wt);

    const dim3 rg(1024), rb(256);
    const dim3 sg(512), sb(256);
    const dim3 qg(256), qb(256);

    // pass A: uniform c = 1/32
    caps_sweep<0><<<rg, rb, 0, stream>>>(Wt, xT2, nullptr, nullptr, nullptr, s_part);
    squash_reduce<<<qg, qb, 0, stream>>>(s_part, nullptr, v1);

    // pass B: d1 = sum_p v1*u_hat ; c2 = softmax(d1) ; s2
    caps_sweep<1><<<rg, rb, 0, stream>>>(Wt, xT2, v1, nullptr, dbuf, nullptr);
    softmax_dc<<<sg, sb, 0, stream>>>(dbuf, cbuf);
    caps_sweep<2><<<rg, rb, 0, stream>>>(Wt, xT2, nullptr, cbuf, nullptr, s_part);
    squash_reduce<<<qg, qb, 0, stream>>>(s_part, v1, vs);     // vs = v1 + v2

    // pass C: logits = sum_p (v1+v2)*u_hat (linearity)
    caps_sweep<1><<<rg, rb, 0, stream>>>(Wt, xT2, vs, nullptr, dbuf, nullptr);
    softmax_dc<<<sg, sb, 0, stream>>>(dbuf, cbuf);
    caps_sweep<2><<<rg, rb, 0, stream>>>(Wt, xT2, nullptr, cbuf, nullptr, s_part);
    squash_reduce<<<qg, qb, 0, stream>>>(s_part, nullptr, out);
}